// Round 11
// baseline (303.647 us; speedup 1.0000x reference)
//
#include <hip/hip_runtime.h>

namespace {

typedef float v4f __attribute__((ext_vector_type(4)));
typedef float v2f __attribute__((ext_vector_type(2)));

constexpr int   kB     = 32768;
constexpr int   kT     = 50;
constexpr float kDT    = 0.01f;
constexpr float kGamma = 0.1f;
constexpr float kSigma = 0.2f;
constexpr float kTau   = 0.5f;

// Packed-weight workspace layout (float offsets). All v2f reads 8B-aligned.
constexpr int WS_L1  = 0;              // [2 mlps][10 rows][20]  b, w_t, wx0..15, pad2
constexpr int WS_L2  = WS_L1  + 400;   // [2][10][12]            b, 0, w0..9
constexpr int WS_L3  = WS_L2  + 240;   // [24][12] rows: q0 zv0-7, q1 zv8-15, q2 u0-3, q3 u4-7
constexpr int WS_UPD = WS_L3  + 288;   // [16][80]  Arow16 Brow8 Crow16 Drow8 Acol16 Ccol16
constexpr int WS_DH  = WS_UPD + 1280;  // [8][32]   Bcol16 Dcol16

__device__ __forceinline__ float ftanh(float x) {
  float e = exp2f(x * 2.8853900817779268f);   // exp(2x) via exp2
  return 1.0f - 2.0f * __builtin_amdgcn_rcpf(e + 1.0f);
}

__device__ __forceinline__ v2f lo2(v4f a) { return __builtin_shufflevector(a, a, 0, 1); }
__device__ __forceinline__ v2f hi2(v4f a) { return __builtin_shufflevector(a, a, 2, 3); }

// ---------------- prep: pack weights in per-wave consumption order ----------
__global__ __launch_bounds__(256) void prep_kernel(
    const float* __restrict__ A,   const float* __restrict__ Bm,
    const float* __restrict__ Cm,  const float* __restrict__ Dm,
    const float* __restrict__ pW1, const float* __restrict__ pb1,
    const float* __restrict__ pW2, const float* __restrict__ pb2,
    const float* __restrict__ pW3, const float* __restrict__ pb3,
    const float* __restrict__ zW1, const float* __restrict__ zb1,
    const float* __restrict__ zW2, const float* __restrict__ zb2,
    const float* __restrict__ zW3, const float* __restrict__ zb3,
    float* __restrict__ ws, float* __restrict__ out)
{
  const int tid = threadIdx.x;
  if (tid < 2) out[tid] = 0.0f;   // harness re-poisons out each replay
  // L1: m=0 -> z rows 0..9 ; m=1 -> phi rows 0..9
  for (int c = tid; c < 20; c += 256) {
    int m = c / 10, row = c % 10;
    const float* W = m ? pW1 : zW1;
    const float* b = m ? pb1 : zb1;
    float* d = ws + WS_L1 + c * 20;
    d[0] = b[row];
    for (int k = 0; k < 17; ++k) d[1 + k] = W[k * 10 + row];
    d[18] = 0.f; d[19] = 0.f;
  }
  // L2: [b, 0, w0..9]
  for (int c = tid; c < 20; c += 256) {
    int m = c / 10, row = c % 10;
    const float* W = m ? pW2 : zW2;
    const float* b = m ? pb2 : zb2;
    float* d = ws + WS_L2 + c * 12;
    d[0] = b[row]; d[1] = 0.f;
    for (int k = 0; k < 10; ++k) d[2 + k] = W[k * 10 + row];
  }
  // L3: [b, 0, w0..9]; rows 0..15 zv, 16..23 u
  for (int c = tid; c < 24; c += 256) {
    float* d = ws + WS_L3 + c * 12;
    d[1] = 0.f;
    if (c < 16) {
      d[0] = zb3[c];
      for (int k = 0; k < 10; ++k) d[2 + k] = zW3[k * 16 + c];
    } else {
      int row = c - 16;
      d[0] = pb3[row];
      for (int k = 0; k < 10; ++k) d[2 + k] = pW3[k * 8 + row];
    }
  }
  // UPD: per state row i: A row, B row, C row, D row, A col, C col
  for (int i = tid; i < 16; i += 256) {
    float* d = ws + WS_UPD + i * 80;
    for (int j = 0; j < 16; ++j) d[j]      = A [i * 16 + j];
    for (int j = 0; j < 8;  ++j) d[16 + j] = Bm[i * 8  + j];
    for (int j = 0; j < 16; ++j) d[24 + j] = Cm[i * 16 + j];
    for (int j = 0; j < 8;  ++j) d[40 + j] = Dm[i * 8  + j];
    for (int j = 0; j < 16; ++j) d[48 + j] = A [j * 16 + i];
    for (int j = 0; j < 16; ++j) d[64 + j] = Cm[j * 16 + i];
  }
  // DH: per control row i: B col, D col
  for (int i = tid; i < 8; i += 256) {
    float* d = ws + WS_DH + i * 32;
    for (int j = 0; j < 16; ++j) d[j]      = Bm[j * 8 + i];
    for (int j = 0; j < 16; ++j) d[16 + j] = Dm[j * 8 + i];
  }
}

// Wave-specialized UPD + dH, packed-fp32 (v2f -> v_pk_fma_f32).
template <int Q>
__device__ __forceinline__ void upd_body(
    const float* __restrict__ Wup, const float* __restrict__ Wdh,
    const v4f x4[4], const v4f y4[4], const v4f zvf[4], const v4f uff[2],
    float dwv, float* __restrict__ Xn, float* __restrict__ Yn, float& s2)
{
  v2f x2[8], y2[8], z2[8], u2[4];
#pragma unroll
  for (int c = 0; c < 4; ++c) {
    x2[2 * c] = lo2(x4[c]);  x2[2 * c + 1] = hi2(x4[c]);
    y2[2 * c] = lo2(y4[c]);  y2[2 * c + 1] = hi2(y4[c]);
    z2[2 * c] = lo2(zvf[c]); z2[2 * c + 1] = hi2(zvf[c]);
  }
#pragma unroll
  for (int c = 0; c < 2; ++c) { u2[2 * c] = lo2(uff[c]); u2[2 * c + 1] = hi2(uff[c]); }

#pragma unroll
  for (int r = 0; r < 4; ++r) {
    const float* w = Wup + r * 80;        // state row i = 4Q + r
    v2f dx = {kGamma, 0.f}, fx = {kSigma, 0.f};
#pragma unroll
    for (int c = 0; c < 8; ++c) {
      dx += *(const v2f*)(w + 2 * c)      * x2[c];
      fx += *(const v2f*)(w + 24 + 2 * c) * x2[c];
    }
#pragma unroll
    for (int c = 0; c < 4; ++c) {
      dx += *(const v2f*)(w + 16 + 2 * c) * u2[c];
      fx += *(const v2f*)(w + 40 + 2 * c) * u2[c];
    }
    const float xi = x4[Q][r];
    const float yi = y4[Q][r];
    const float zi = zvf[Q][r];
    v2f dy = {xi, 0.f};
#pragma unroll
    for (int c = 0; c < 8; ++c)
      dy += *(const v2f*)(w + 48 + 2 * c) * y2[c] + *(const v2f*)(w + 64 + 2 * c) * z2[c];
    Xn[r] = xi + kDT * (dx[0] + dx[1]) + dwv * (fx[0] + fx[1]);
    Yn[r] = yi - kDT * (dy[0] + dy[1]) + dwv * zi;
  }
#pragma unroll
  for (int r = 0; r < 2; ++r) {
    const int i = 2 * Q + r;
    const float* w = Wdh + i * 32;
    v2f dh = {uff[i >> 2][i & 3], 0.f};
#pragma unroll
    for (int c = 0; c < 8; ++c)
      dh += *(const v2f*)(w + 2 * c) * y2[c] + *(const v2f*)(w + 16 + 2 * c) * z2[c];
    const float d = dh[0] + dh[1];
    s2 += d * d;
  }
}

// ---------------- main: 4 waves / 64 elements, 2 barriers per step ----------
// R9 structure + amdgpu_waves_per_eu(2,2): min AND MAX 2 waves/EU. The max
// clamp is the key — launch_bounds(256,2) only set a minimum, so the
// allocator still targeted 8-waves occupancy (64-VGPR budget, chose 48) and
// juggled the 56-float pinned live set via remat (measured ~1670 VALU
// instr/wave-step vs ~610 hand count). With max=2 the budget is 256 VGPRs.
__global__ __launch_bounds__(256)
__attribute__((amdgpu_waves_per_eu(2, 2)))
void bsde_kernel(
    const float* __restrict__ dw,  const float* __restrict__ X0,
    const float* __restrict__ yW1, const float* __restrict__ yb1,
    const float* __restrict__ yW2, const float* __restrict__ yb2,
    const float* __restrict__ yW3, const float* __restrict__ yb3,
    const float* __restrict__ ws,  float* __restrict__ out)
{
  __shared__ float XYt[64][36];   // dwords 0..15 = X, 16..31 = Y
  __shared__ float ZUt[64][28];   // 0..15 = Zv, 16..23 = u

  const int lane = threadIdx.x & 63;
  const int q    = __builtin_amdgcn_readfirstlane((int)(threadIdx.x >> 6));
  const int e    = blockIdx.x * 64 + lane;

  const int m      = q >> 1;                                   // 0=z, 1=phi
  const int l3off  = (q & 2) ? (192 + (q & 1) * 48) : (q * 96);
  const float* Wl1 = ws + WS_L1  + m * 200;
  const float* Wl2 = ws + WS_L2  + m * 120;
  const float* Wl3 = ws + WS_L3  + l3off;
  const float* Wup = ws + WS_UPD + q * 320;
  const float* Wdh = ws + WS_DH;

  // ---- X0 load (b128) + Y0 MLP (redundant per wave, one-time) ----
  v4f x4[4], y4[4];
#pragma unroll
  for (int c = 0; c < 4; ++c) x4[c] = *(const v4f*)&X0[e * 16 + 4 * c];

  {
    float h1t[10], h2t[10];
#pragma unroll
    for (int r = 0; r < 10; ++r) {
      float s = yb1[r];
#pragma unroll
      for (int c = 0; c < 4; ++c)
#pragma unroll
        for (int j = 0; j < 4; ++j) s += x4[c][j] * yW1[(4 * c + j) * 10 + r];
      h1t[r] = ftanh(s);
    }
#pragma unroll
    for (int r = 0; r < 10; ++r) {
      float s = yb2[r];
#pragma unroll
      for (int k = 0; k < 10; ++k) s += h1t[k] * yW2[k * 10 + r];
      h2t[r] = ftanh(s);
    }
#pragma unroll
    for (int r = 0; r < 16; ++r) {
      float s = yb3[r];
#pragma unroll
      for (int k = 0; k < 10; ++k) s += h2t[k] * yW3[k * 16 + r];
      y4[r >> 2][r & 3] = s;
    }
  }

  // Seed XYt (wave 0 only; values bit-identical across waves), then barrier.
  if (q == 0) {
#pragma unroll
    for (int c = 0; c < 4; ++c) {
      *(v4f*)&XYt[lane][4 * c]      = x4[c];
      *(v4f*)&XYt[lane][16 + 4 * c] = y4[c];
    }
  }
  __syncthreads();

  float lcp = 0.0f;
  float Xn[4], Yn[4];
  float dwv = dw[e];   // t=0 increment

  // ------------------------------- time loop -------------------------------
#pragma unroll 1
  for (int t = 0; t < kT; ++t) {
    float dwn = (t < kT - 1) ? dw[(t + 1) * kB + e] : 0.0f;
    const float tv = (float)t * kDT;
    const float wt = (t == 0 || t == kT - 1) ? 1.0f : 2.0f;

    // Read full state (b128), pin in registers.
#pragma unroll
    for (int c = 0; c < 4; ++c) {
      x4[c] = *(const v4f*)&XYt[lane][4 * c];
      y4[c] = *(const v4f*)&XYt[lane][16 + 4 * c];
    }
    asm volatile("" : "+v"(x4[0]), "+v"(x4[1]), "+v"(x4[2]), "+v"(x4[3]),
                      "+v"(y4[0]), "+v"(y4[1]), "+v"(y4[2]), "+v"(y4[3]));

    v2f xp[8];
#pragma unroll
    for (int c = 0; c < 4; ++c) { xp[2 * c] = lo2(x4[c]); xp[2 * c + 1] = hi2(x4[c]); }

    // L1: full 10 rows of own MLP (packed dots, k=16 -> 8 pk)
    float hh[10];
#pragma unroll
    for (int r = 0; r < 10; ++r) {
      const float* w = Wl1 + r * 20;
      v2f bw = *(const v2f*)w;                 // [bias, w_t]
      v2f acc = {bw[0] + tv * bw[1], 0.f};
#pragma unroll
      for (int c = 0; c < 8; ++c) acc += *(const v2f*)(w + 2 + 2 * c) * xp[c];
      hh[r] = ftanh(acc[0] + acc[1]);
    }
    v2f hp[5];
#pragma unroll
    for (int k = 0; k < 5; ++k) { v2f t2 = {hh[2 * k], hh[2 * k + 1]}; hp[k] = t2; }

    // L2: full 10 rows (5 pk each)
    float gg[10];
#pragma unroll
    for (int r = 0; r < 10; ++r) {
      const float* w = Wl2 + r * 12;
      v2f acc = {w[0], 0.f};
#pragma unroll
      for (int k = 0; k < 5; ++k) acc += *(const v2f*)(w + 2 + 2 * k) * hp[k];
      gg[r] = ftanh(acc[0] + acc[1]);
    }
    v2f gp[5];
#pragma unroll
    for (int k = 0; k < 5; ++k) { v2f t2 = {gg[2 * k], gg[2 * k + 1]}; gp[k] = t2; }

    // L3: z-waves 8 Zv rows each; phi-waves 4 u rows each
    if (q < 2) {
      float z[8];
#pragma unroll
      for (int r = 0; r < 8; ++r) {
        const float* w = Wl3 + r * 12;
        v2f acc = {w[0], 0.f};
#pragma unroll
        for (int k = 0; k < 5; ++k) acc += *(const v2f*)(w + 2 + 2 * k) * gp[k];
        z[r] = acc[0] + acc[1];
      }
      v4f z0 = {z[0], z[1], z[2], z[3]}, z1 = {z[4], z[5], z[6], z[7]};
      *(v4f*)&ZUt[lane][8 * q]     = z0;
      *(v4f*)&ZUt[lane][8 * q + 4] = z1;
    } else {
      float z[4];
#pragma unroll
      for (int r = 0; r < 4; ++r) {
        const float* w = Wl3 + r * 12;
        v2f acc = {w[0], 0.f};
#pragma unroll
        for (int k = 0; k < 5; ++k) acc += *(const v2f*)(w + 2 + 2 * k) * gp[k];
        z[r] = acc[0] + acc[1];
      }
      v4f zz = {z[0], z[1], z[2], z[3]};
      *(v4f*)&ZUt[lane][16 + 4 * (q - 2)] = zz;
    }
    __syncthreads();                       // B1: ZU visible

    v4f zvf[4], uff[2];
#pragma unroll
    for (int c = 0; c < 4; ++c) zvf[c] = *(const v4f*)&ZUt[lane][4 * c];
#pragma unroll
    for (int c = 0; c < 2; ++c) uff[c] = *(const v4f*)&ZUt[lane][16 + 4 * c];
    asm volatile("" : "+v"(zvf[0]), "+v"(zvf[1]), "+v"(zvf[2]), "+v"(zvf[3]),
                      "+v"(uff[0]), "+v"(uff[1]));

    // UPD + dH, wave-specialized (uniform branch)
    float s2 = 0.0f;
    if      (q == 0) upd_body<0>(Wup, Wdh, x4, y4, zvf, uff, dwv, Xn, Yn, s2);
    else if (q == 1) upd_body<1>(Wup, Wdh, x4, y4, zvf, uff, dwv, Xn, Yn, s2);
    else if (q == 2) upd_body<2>(Wup, Wdh, x4, y4, zvf, uff, dwv, Xn, Yn, s2);
    else             upd_body<3>(Wup, Wdh, x4, y4, zvf, uff, dwv, Xn, Yn, s2);
    lcp += (0.5f * kDT * kTau * kTau) * wt * s2;

    // Publish own rows (b128)
    {
      v4f xs = {Xn[0], Xn[1], Xn[2], Xn[3]};
      v4f ys = {Yn[0], Yn[1], Yn[2], Yn[3]};
      *(v4f*)&XYt[lane][4 * q]      = xs;
      *(v4f*)&XYt[lane][16 + 4 * q] = ys;
    }
    dwv = dwn;
    __syncthreads();                       // B2: XY visible
  }

  // ---- losses ----
#pragma unroll
  for (int c = 0; c < 4; ++c) {
    x4[c] = *(const v4f*)&XYt[lane][4 * c];
    y4[c] = *(const v4f*)&XYt[lane][16 + 4 * c];
  }
  float bp = 0.0f;
  if (q == 0) {
#pragma unroll
    for (int c = 0; c < 4; ++c)
#pragma unroll
      for (int j = 0; j < 4; ++j) {
        float d = y4[c][j] - x4[c][j];
        bp += d * d;
      }
  }
#pragma unroll
  for (int s = 32; s > 0; s >>= 1) {
    bp  += __shfl_down(bp,  s, 64);
    lcp += __shfl_down(lcp, s, 64);
  }
  if (lane == 0) {
    if (q == 0) atomicAdd(&out[0], bp * (1.0f / (float)kB));
    atomicAdd(&out[1], lcp * (1.0f / (float)kB));
  }
}

} // namespace

extern "C" void kernel_launch(void* const* d_in, const int* in_sizes, int n_in,
                              void* d_out, int out_size, void* d_ws, size_t ws_size,
                              hipStream_t stream) {
  (void)in_sizes; (void)n_in; (void)ws_size; (void)out_size;

  const float* dw  = (const float*)d_in[0];
  const float* X0  = (const float*)d_in[1];
  const float* A   = (const float*)d_in[2];
  const float* Bm  = (const float*)d_in[3];
  const float* Cm  = (const float*)d_in[4];
  const float* Dm  = (const float*)d_in[5];
  const float* pW1 = (const float*)d_in[6];
  const float* pb1 = (const float*)d_in[7];
  const float* pW2 = (const float*)d_in[8];
  const float* pb2 = (const float*)d_in[9];
  const float* pW3 = (const float*)d_in[10];
  const float* pb3 = (const float*)d_in[11];
  const float* zW1 = (const float*)d_in[12];
  const float* zb1 = (const float*)d_in[13];
  const float* zW2 = (const float*)d_in[14];
  const float* zb2 = (const float*)d_in[15];
  const float* zW3 = (const float*)d_in[16];
  const float* zb3 = (const float*)d_in[17];
  const float* yW1 = (const float*)d_in[18];
  const float* yb1 = (const float*)d_in[19];
  const float* yW2 = (const float*)d_in[20];
  const float* yb2 = (const float*)d_in[21];
  const float* yW3 = (const float*)d_in[22];
  const float* yb3 = (const float*)d_in[23];
  float* out = (float*)d_out;
  float* ws  = (float*)d_ws;

  prep_kernel<<<1, 256, 0, stream>>>(
      A, Bm, Cm, Dm,
      pW1, pb1, pW2, pb2, pW3, pb3,
      zW1, zb1, zW2, zb2, zW3, zb3, ws, out);

  bsde_kernel<<<kB / 64, 256, 0, stream>>>(
      dw, X0, yW1, yb1, yW2, yb2, yW3, yb3, ws, out);
}